// Round 1
// 147.787 us; speedup vs baseline: 1.0006x; 1.0006x over previous
//
#include <hip/hip_runtime.h>
#include <math.h>

// Deformation4D: N=1M gaussians, K_NB=10 neighbors, K_TOTAL=300 control points.
//
// v2 strategy: the v1 kernel was LDS-gather bound (5.8M bank-conflict cycles,
// 4x ds_read_b128 per neighbor). Key algebra: every entry of R(q_hat) is LINEAR
// in the 10 quadratic monomials of q_hat, so
//   sum_k w_k R(q_hat_k) = A(M),  M = sum_k w_k q_hat_k q_hat_k^T.
// We therefore gather only {q_hat (16B), b (16B)} per neighbor (b = p + t - R p)
// -- 32B instead of 64B -- accumulate the 9 monomials + q-sum + b-sum, and
// reconstruct sum(wR) in the epilogue. LDS traffic and conflicts halve.
//
// Table build is hoisted to a 1-dispatch precompute kernel into d_ws so the
// main kernel's staging is a coalesced 9.6KB copy (fallback: fused staging).
//
// LDS layout: s4[0..K) = q_hat (w,x,y,z) ; s4[K..2K) = b (x,y,z,pad).

__device__ __forceinline__ void compute_cp(
    const float* __restrict__ ctrl_trans,
    const float* __restrict__ ctrl_rot,
    const float* __restrict__ ctrl_pos,
    int cp, float4* q_out, float4* b_out)
{
    float qw = ctrl_rot[cp * 4 + 0];
    float qx = ctrl_rot[cp * 4 + 1];
    float qy = ctrl_rot[cp * 4 + 2];
    float qz = ctrl_rot[cp * 4 + 3];
    float n   = sqrtf(qw * qw + qx * qx + qy * qy + qz * qz);
    float inv = 1.0f / fmaxf(n, 1e-8f);
    float w = qw * inv, x = qx * inv, y = qy * inv, z = qz * inv;
    float R00 = 1.0f - 2.0f * (y * y + z * z);
    float R01 = 2.0f * (x * y - w * z);
    float R02 = 2.0f * (x * z + w * y);
    float R10 = 2.0f * (x * y + w * z);
    float R11 = 1.0f - 2.0f * (x * x + z * z);
    float R12 = 2.0f * (y * z - w * x);
    float R20 = 2.0f * (x * z - w * y);
    float R21 = 2.0f * (y * z + w * x);
    float R22 = 1.0f - 2.0f * (x * x + y * y);
    float px = ctrl_pos[cp * 3 + 0];
    float py = ctrl_pos[cp * 3 + 1];
    float pz = ctrl_pos[cp * 3 + 2];
    float tx = ctrl_trans[cp * 3 + 0];
    float ty = ctrl_trans[cp * 3 + 1];
    float tz = ctrl_trans[cp * 3 + 2];
    *q_out = make_float4(w, x, y, z);
    *b_out = make_float4(px + tx - (R00 * px + R01 * py + R02 * pz),
                         py + ty - (R10 * px + R11 * py + R12 * pz),
                         pz + tz - (R20 * px + R21 * py + R22 * pz),
                         0.0f);
}

__global__ __launch_bounds__(256) void build_table_kernel(
    const float* __restrict__ ctrl_trans,
    const float* __restrict__ ctrl_rot,
    const float* __restrict__ ctrl_pos,
    float4* __restrict__ table, int K_TOTAL)
{
    int cp = blockIdx.x * blockDim.x + threadIdx.x;
    if (cp >= K_TOTAL) return;
    float4 q, b;
    compute_cp(ctrl_trans, ctrl_rot, ctrl_pos, cp, &q, &b);
    table[cp] = q;
    table[K_TOTAL + cp] = b;
}

// KNB > 0: compile-time neighbor count (fully unrolled). KNB == 0: runtime.
template <int KNB>
__device__ __forceinline__ void deform_body(
    const float4* __restrict__ s4,
    const float* __restrict__ means,
    const float* __restrict__ quats,
    const float* __restrict__ weights,
    const int*   __restrict__ indices,
    float* __restrict__ out_means,
    float* __restrict__ out_quats,
    int i, int K_TOTAL, int K_NB_rt)
{
    const int kn = (KNB > 0) ? KNB : K_NB_rt;
    const int*   idx_row = indices + (long long)i * kn;
    const float* w_row   = weights + (long long)i * kn;

    float W = 0.0f;
    float Mxx = 0.0f, Myy = 0.0f, Mzz = 0.0f;
    float Mxy = 0.0f, Mxz = 0.0f, Myz = 0.0f;
    float Mwx = 0.0f, Mwy = 0.0f, Mwz = 0.0f;
    float qsw = 0.0f, qsx = 0.0f, qsy = 0.0f, qsz = 0.0f;
    float bsx = 0.0f, bsy = 0.0f, bsz = 0.0f;

#pragma unroll
    for (int k = 0; k < kn; k++) {
        int   cp = idx_row[k];
        float w  = w_row[k];
        float4 q = s4[cp];             // (w,x,y,z) normalized
        float4 b = s4[K_TOTAL + cp];   // (bx,by,bz,_)
        float tw = w * q.x, tx = w * q.y, ty = w * q.z, tz = w * q.w;
        W += w;
        Mxx = fmaf(tx, q.y, Mxx);
        Myy = fmaf(ty, q.z, Myy);
        Mzz = fmaf(tz, q.w, Mzz);
        Mxy = fmaf(tx, q.z, Mxy);
        Mxz = fmaf(tx, q.w, Mxz);
        Myz = fmaf(ty, q.w, Myz);
        Mwx = fmaf(tw, q.y, Mwx);
        Mwy = fmaf(tw, q.z, Mwy);
        Mwz = fmaf(tw, q.w, Mwz);
        qsw += tw; qsx += tx; qsy += ty; qsz += tz;
        bsx = fmaf(w, b.x, bsx);
        bsy = fmaf(w, b.y, bsy);
        bsz = fmaf(w, b.z, bsz);
    }

    float mx = means[i * 3 + 0];
    float my = means[i * 3 + 1];
    float mz = means[i * 3 + 2];

    // A = sum_k w_k R(q_hat_k), reconstructed from the monomial sums.
    float A00 = W - 2.0f * (Myy + Mzz);
    float A01 = 2.0f * (Mxy - Mwz);
    float A02 = 2.0f * (Mxz + Mwy);
    float A10 = 2.0f * (Mxy + Mwz);
    float A11 = W - 2.0f * (Mxx + Mzz);
    float A12 = 2.0f * (Myz - Mwx);
    float A20 = 2.0f * (Mxz - Mwy);
    float A21 = 2.0f * (Myz + Mwx);
    float A22 = W - 2.0f * (Mxx + Myy);

    out_means[i * 3 + 0] = fmaf(A00, mx, fmaf(A01, my, fmaf(A02, mz, bsx)));
    out_means[i * 3 + 1] = fmaf(A10, mx, fmaf(A11, my, fmaf(A12, mz, bsy)));
    out_means[i * 3 + 2] = fmaf(A20, mx, fmaf(A21, my, fmaf(A22, mz, bsz)));

    // blended quaternion: normalize(sum w q_hat), then Hamilton-multiply.
    float n   = sqrtf(qsw * qsw + qsx * qsx + qsy * qsy + qsz * qsz);
    float inv = 1.0f / fmaxf(n, 1e-8f);
    float bw = qsw * inv, bx = qsx * inv, by = qsy * inv, bz = qsz * inv;

    float4 g = ((const float4*)quats)[i];
    float gw = g.x, gx = g.y, gy = g.z, gz = g.w;

    float ow = bw * gw - bx * gx - by * gy - bz * gz;
    float ox = bw * gx + bx * gw + by * gz - bz * gy;
    float oy = bw * gy - bx * gz + by * gw + bz * gx;
    float oz = bw * gz + bx * gy - by * gx + bz * gw;

    float4* oq = (float4*)(out_quats + (long long)i * 4);
    *oq = make_float4(ow, ox, oy, oz);
}

// Fast path: table precomputed in d_ws, staging is a coalesced copy.
template <int KNB>
__global__ __launch_bounds__(256) void deform_kernel(
    const float* __restrict__ means,
    const float* __restrict__ quats,
    const float* __restrict__ weights,
    const float4* __restrict__ table,
    const int*   __restrict__ indices,
    float* __restrict__ out_means,
    float* __restrict__ out_quats,
    int N, int K_TOTAL, int K_NB_rt)
{
    extern __shared__ float4 s4[];
    int nelem = 2 * K_TOTAL;
    for (int t = threadIdx.x; t < nelem; t += blockDim.x) s4[t] = table[t];
    __syncthreads();

    int i = blockIdx.x * blockDim.x + threadIdx.x;
    if (i >= N) return;
    deform_body<KNB>(s4, means, quats, weights, indices, out_means, out_quats,
                     i, K_TOTAL, K_NB_rt);
}

// Fallback: build the table in-kernel (no workspace needed).
template <int KNB>
__global__ __launch_bounds__(256) void deform_fused_kernel(
    const float* __restrict__ means,
    const float* __restrict__ quats,
    const float* __restrict__ weights,
    const float* __restrict__ ctrl_trans,
    const float* __restrict__ ctrl_rot,
    const float* __restrict__ ctrl_pos,
    const int*   __restrict__ indices,
    float* __restrict__ out_means,
    float* __restrict__ out_quats,
    int N, int K_TOTAL, int K_NB_rt)
{
    extern __shared__ float4 s4[];
    for (int cp = threadIdx.x; cp < K_TOTAL; cp += blockDim.x) {
        float4 q, b;
        compute_cp(ctrl_trans, ctrl_rot, ctrl_pos, cp, &q, &b);
        s4[cp] = q;
        s4[K_TOTAL + cp] = b;
    }
    __syncthreads();

    int i = blockIdx.x * blockDim.x + threadIdx.x;
    if (i >= N) return;
    deform_body<KNB>(s4, means, quats, weights, indices, out_means, out_quats,
                     i, K_TOTAL, K_NB_rt);
}

extern "C" void kernel_launch(void* const* d_in, const int* in_sizes, int n_in,
                              void* d_out, int out_size, void* d_ws, size_t ws_size,
                              hipStream_t stream) {
    const float* means      = (const float*)d_in[0];
    const float* quats      = (const float*)d_in[1];
    const float* weights    = (const float*)d_in[2];
    const float* ctrl_trans = (const float*)d_in[3];
    const float* ctrl_rot   = (const float*)d_in[4];
    const float* ctrl_pos   = (const float*)d_in[5];
    const int*   indices    = (const int*)d_in[6];

    int N       = in_sizes[0] / 3;
    int K_NB    = in_sizes[2] / N;       // weights is N*K_NB
    int K_TOTAL = in_sizes[3] / 3;       // ctrl_translations is K_TOTAL*3

    float* out_means = (float*)d_out;
    float* out_quats = (float*)d_out + (long long)N * 3;

    int block = 256;
    int grid  = (N + block - 1) / block;
    size_t tbl_bytes = (size_t)K_TOTAL * 2 * sizeof(float4);
    size_t smem = tbl_bytes;

    if (d_ws != nullptr && ws_size >= tbl_bytes) {
        int gb = (K_TOTAL + block - 1) / block;
        build_table_kernel<<<gb, block, 0, stream>>>(
            ctrl_trans, ctrl_rot, ctrl_pos, (float4*)d_ws, K_TOTAL);
        if (K_NB == 10) {
            deform_kernel<10><<<grid, block, smem, stream>>>(
                means, quats, weights, (const float4*)d_ws, indices,
                out_means, out_quats, N, K_TOTAL, K_NB);
        } else {
            deform_kernel<0><<<grid, block, smem, stream>>>(
                means, quats, weights, (const float4*)d_ws, indices,
                out_means, out_quats, N, K_TOTAL, K_NB);
        }
    } else {
        if (K_NB == 10) {
            deform_fused_kernel<10><<<grid, block, smem, stream>>>(
                means, quats, weights, ctrl_trans, ctrl_rot, ctrl_pos, indices,
                out_means, out_quats, N, K_TOTAL, K_NB);
        } else {
            deform_fused_kernel<0><<<grid, block, smem, stream>>>(
                means, quats, weights, ctrl_trans, ctrl_rot, ctrl_pos, indices,
                out_means, out_quats, N, K_TOTAL, K_NB);
        }
    }
}